// Round 6
// baseline (219.744 us; speedup 1.0000x reference)
//
#include <hip/hip_runtime.h>
#include <math.h>

#define N_USERS 1000000
#define N_ITEMS 100000
#define EMB 16
#define OUTD 16
#define NH 4
#define HID 32
#define BB 8192
#define SS 200
#define LL 50
#define NSUPP 50000
#define KS_BLOCKS (NSUPP / 16)   // 3125

typedef float v4f __attribute__((ext_vector_type(4)));

// DPP cross-lane helpers (VALU pipe, no LDS). ctrl: quad_perm xor1=0xB1,
// xor2=0x4E; row_ror:4=0x124, row_ror:8=0x128 (rotation = valid butterfly
// step for sum/max within a 16-lane row, qt-class preserving).
#define DPPF(x, ctrl) \
    __int_as_float(__builtin_amdgcn_update_dpp(0, __float_as_int(x), ctrl, 0xF, 0xF, true))

// ---------------------------------------------------------------------------
// Fused setup: blocks [0, KS_BLOCKS) build Ksupp; the rest build qbuf.
// ---------------------------------------------------------------------------
__global__ __launch_bounds__(256) void setup_kernel(
    const float* __restrict__ user_emb,
    const int*   __restrict__ supp_users,
    const float* __restrict__ wk,
    float*       __restrict__ Ksupp,
    const float* __restrict__ item_emb,
    const int*   __restrict__ history,
    const int*   __restrict__ history_len,
    const float* __restrict__ wq,
    float*       __restrict__ qbuf)
{
    int t = threadIdx.x;
    if (blockIdx.x < KS_BLOCKS) {
        // ---- K_supp[h][n][o] = sum_e U[supp[n]][e] * wk[h][e][o], 16 n/block
        __shared__ float s_wk[NH * EMB * OUTD];
        __shared__ float s_u[16][EMB];
        for (int i = t; i < NH * EMB * OUTD; i += 256) s_wk[i] = wk[i];
        int n0 = blockIdx.x * 16;
        {
            int ul = t >> 4, e = t & 15;
            int row = supp_users[n0 + ul];
            s_u[ul][e] = user_emb[(size_t)row * EMB + e];
        }
        __syncthreads();
        int h   = t >> 6;
        int sub = (t >> 4) & 3;
        int o   = t & 15;
#pragma unroll
        for (int r = 0; r < 4; ++r) {
            int ul = sub + 4 * r;
            float acc = 0.f;
#pragma unroll
            for (int e = 0; e < EMB; ++e)
                acc += s_u[ul][e] * s_wk[(h * EMB + e) * OUTD + o];
            Ksupp[((size_t)h * NSUPP + n0 + ul) * OUTD + o] = acc;
        }
    } else {
        // ---- user_init + q: 4 b per block
        __shared__ float s_ui[4][EMB];
        __shared__ float s_wq[NH * EMB * OUTD];
        for (int i = t; i < NH * EMB * OUTD; i += 256) s_wq[i] = wq[i];

        int g    = t >> 6;
        int lane = t & 63;
        int l4   = lane >> 4;
        int e    = lane & 15;
        int b    = (blockIdx.x - KS_BLOCKS) * 4 + g;

        float sum = 0.f;
        for (int l = l4; l < LL; l += 4) {
            int it = __builtin_nontemporal_load(history + (size_t)b * LL + l);
            sum += item_emb[(size_t)it * EMB + e];
        }
        sum += __shfl_xor(sum, 16);
        sum += __shfl_xor(sum, 32);
        if (lane < EMB) s_ui[g][lane] = sum / (float)history_len[b];
        __syncthreads();

        int h = (t >> 4) & 3;
        int o = t & 15;
        float acc = 0.f;
#pragma unroll
        for (int ee = 0; ee < EMB; ++ee)
            acc += s_ui[g][ee] * s_wq[(h * EMB + ee) * OUTD + o];
        qbuf[((size_t)b * NH + h) * OUTD + o] = acc;
    }
}

// ---------------------------------------------------------------------------
// Attention per (h, b): one wave per b, one head per block.
// Quad-cooperative K gather (16 lines/instr). All cross-lane reductions on
// the VALU via DPP except the two row-crossing steps (xor16/xor32).
// Indices loaded directly per-quad (same-address broadcast, 1 line/instr) —
// no ds_bpermute broadcast.
// ---------------------------------------------------------------------------
__global__ __launch_bounds__(256, 4) void attn_kernel(
    const float* __restrict__ Ksupp,
    const float* __restrict__ qbuf,
    const int*   __restrict__ sample_index,
    const float* __restrict__ wv,
    float*       __restrict__ gat)
{
    int blk   = blockIdx.x;
    int h     = (blk & 7) >> 1;
    int btile = ((blk >> 3) << 1) | (blk & 1);
    int wave  = threadIdx.x >> 6;
    int lane  = threadIdx.x & 63;
    int b     = btile * 4 + wave;
    int g     = lane >> 2;      // row slot within a round (16 per round)
    int qt    = lane & 3;       // 16-B quarter of the 64-B row

    // per-quad direct index loads: quad lanes share the address (TA
    // broadcast); 16 consecutive ints per instr = 1 cache line.
    const int* si = sample_index + ((size_t)h * BB + b) * SS;
    int idx[13];
#pragma unroll
    for (int r = 0; r < 13; ++r) {
        int s = r * 16 + g;
        if (s > SS - 1) s = SS - 1;          // r=12, g>=8: clamped, masked below
        idx[r] = __builtin_nontemporal_load(si + s);
    }

    v4f qv = __builtin_nontemporal_load(
        (const v4f*)(qbuf + ((size_t)b * NH + h) * OUTD) + qt);

    const float* Kh = Ksupp + (size_t)h * NSUPP * OUTD;

    // all 13 quad-cooperative gathers in flight
    v4f kq[13];
#pragma unroll
    for (int r = 0; r < 13; ++r)
        kq[r] = *(const v4f*)(Kh + (size_t)idx[r] * OUTD + qt * 4);

    // scores: quarter-dot + intra-quad DPP reduce (quad_perm xor1, xor2)
    float d[13];
#pragma unroll
    for (int r = 0; r < 13; ++r) {
        float p = kq[r].x * qv.x + kq[r].y * qv.y + kq[r].z * qv.z + kq[r].w * qv.w;
        p += DPPF(p, 0xB1);
        p += DPPF(p, 0x4E);
        d[r] = p;
    }
    if (g >= 8) d[12] = -3.0e38f;            // only s<200 valid in round 12

    // wave max: row_ror:4/8 (DPP) then xor16/xor32 (bpermute)
    float m = d[0];
#pragma unroll
    for (int r = 1; r < 13; ++r) m = fmaxf(m, d[r]);
    m = fmaxf(m, DPPF(m, 0x124));
    m = fmaxf(m, DPPF(m, 0x128));
    m = fmaxf(m, __shfl_xor(m, 16));
    m = fmaxf(m, __shfl_xor(m, 32));

    // weights + context quarter accumulation (K rows still live in regs)
    float l = 0.f;
    v4f c = {0.f, 0.f, 0.f, 0.f};
#pragma unroll
    for (int r = 0; r < 13; ++r) {
        float w = __expf(d[r] - m);          // exactly 0 for masked slots
        l += w;
        c += w * kq[r];
    }
    // cross-group reduce (qt-preserving): DPP ror4/ror8, then xor16/xor32
    l   += DPPF(l,   0x124); l   += DPPF(l,   0x128);
    c.x += DPPF(c.x, 0x124); c.x += DPPF(c.x, 0x128);
    c.y += DPPF(c.y, 0x124); c.y += DPPF(c.y, 0x128);
    c.z += DPPF(c.z, 0x124); c.z += DPPF(c.z, 0x128);
    c.w += DPPF(c.w, 0x124); c.w += DPPF(c.w, 0x128);
    l   += __shfl_xor(l,   16); l   += __shfl_xor(l,   32);
    c.x += __shfl_xor(c.x, 16); c.x += __shfl_xor(c.x, 32);
    c.y += __shfl_xor(c.y, 16); c.y += __shfl_xor(c.y, 32);
    c.z += __shfl_xor(c.z, 16); c.z += __shfl_xor(c.z, 32);
    c.w += __shfl_xor(c.w, 16); c.w += __shfl_xor(c.w, 32);
    float inv = 1.f / l;

    // gat[b][h*16+g]: group g owns output column g; lane covers its quarter's
    // rows of wv, intra-quad DPP reduce.
    float part = c.x * wv[((size_t)h * OUTD + qt * 4 + 0) * OUTD + g]
               + c.y * wv[((size_t)h * OUTD + qt * 4 + 1) * OUTD + g]
               + c.z * wv[((size_t)h * OUTD + qt * 4 + 2) * OUTD + g]
               + c.w * wv[((size_t)h * OUTD + qt * 4 + 3) * OUTD + g];
    part += DPPF(part, 0xB1);
    part += DPPF(part, 0x4E);
    if (qt == 0)
        gat[(size_t)b * (NH * OUTD) + h * OUTD + g] = part * inv;
}

// ---------------------------------------------------------------------------
// Epilogue per b (4 b per 256-thread block, one wave per b).
// ---------------------------------------------------------------------------
__global__ __launch_bounds__(256) void epilogue_kernel(
    const float* __restrict__ gat,
    const float* __restrict__ item_emb,
    const float* __restrict__ w_out,
    const float* __restrict__ l1_w, const float* __restrict__ l1_b,
    const float* __restrict__ l2_w, const float* __restrict__ l2_b,
    const float* __restrict__ l3_w, const float* __restrict__ l3_b,
    const float* __restrict__ user_bias, const float* __restrict__ item_bias,
    const int*   __restrict__ x,
    float*       __restrict__ out)
{
    int t    = threadIdx.x;
    int g    = t >> 6;
    int lane = t & 63;
    int b    = blockIdx.x * 4 + g;

    __shared__ float s_gat[4][NH * OUTD];
    __shared__ float s_ue[4][OUTD];
    __shared__ float s_ie[4][EMB];
    __shared__ float s_x1[4][HID];
    __shared__ float s_x2[4][HID / 2];

    int uid = x[(size_t)b * 2 + 0];
    int iid = x[(size_t)b * 2 + 1];

    s_gat[g][lane] = gat[(size_t)b * (NH * OUTD) + lane];
    if (lane < EMB) s_ie[g][lane] = item_emb[(size_t)iid * EMB + lane];
    __syncthreads();

    if (lane < OUTD) {
        float acc = 0.f;
#pragma unroll
        for (int j = 0; j < NH * OUTD; ++j) acc += s_gat[g][j] * w_out[j * OUTD + lane];
        s_ue[g][lane] = acc;
    }
    __syncthreads();

    if (lane < HID) {
        float acc = l1_b[lane];
#pragma unroll
        for (int i = 0; i < EMB; ++i) {
            float ue = s_ue[g][i], ie = s_ie[g][i];
            acc += ue * l1_w[i * HID + lane]
                 + ie * l1_w[(EMB + i) * HID + lane]
                 + ue * ie * l1_w[(2 * EMB + i) * HID + lane];
        }
        s_x1[g][lane] = tanhf(acc);
    }
    __syncthreads();

    if (lane < HID / 2) {
        float acc = l2_b[lane];
#pragma unroll
        for (int j = 0; j < HID; ++j) acc += s_x1[g][j] * l2_w[j * (HID / 2) + lane];
        s_x2[g][lane] = tanhf(acc);
    }
    __syncthreads();

    if (lane == 0) {
        float x3 = l3_b[0];
#pragma unroll
        for (int j = 0; j < HID / 2; ++j) x3 += s_x2[g][j] * l3_w[j];
        float ratings = 0.f;
#pragma unroll
        for (int o = 0; o < OUTD; ++o) ratings += s_ue[g][o] * s_ie[g][o];
        out[b] = 0.5f * (ratings + x3) + user_bias[uid] + item_bias[iid];
    }
}

// ---------------------------------------------------------------------------
extern "C" void kernel_launch(void* const* d_in, const int* in_sizes, int n_in,
                              void* d_out, int out_size, void* d_ws, size_t ws_size,
                              hipStream_t stream) {
    const float* user_embedding = (const float*)d_in[0];
    const float* item_embedding = (const float*)d_in[1];
    const float* wq             = (const float*)d_in[2];
    const float* wk             = (const float*)d_in[3];
    const float* wv             = (const float*)d_in[4];
    const float* w_out          = (const float*)d_in[5];
    const float* l1_w           = (const float*)d_in[6];
    const float* l1_b           = (const float*)d_in[7];
    const float* l2_w           = (const float*)d_in[8];
    const float* l2_b           = (const float*)d_in[9];
    const float* l3_w           = (const float*)d_in[10];
    const float* l3_b           = (const float*)d_in[11];
    const float* user_bias      = (const float*)d_in[12];
    const float* item_bias      = (const float*)d_in[13];
    const int*   x              = (const int*)d_in[14];
    const int*   history        = (const int*)d_in[15];
    const int*   history_len    = (const int*)d_in[16];
    const int*   supp_users     = (const int*)d_in[17];
    const int*   sample_index   = (const int*)d_in[18];
    float* out = (float*)d_out;

    char* ws = (char*)d_ws;
    float* Ksupp = (float*)ws;                                    // 12.8 MB
    ws += (size_t)NH * NSUPP * OUTD * sizeof(float);
    float* qbuf  = (float*)ws;                                    // 2 MB
    ws += (size_t)BB * NH * OUTD * sizeof(float);
    float* gat   = (float*)ws;                                    // 2 MB

    setup_kernel<<<KS_BLOCKS + BB / 4, 256, 0, stream>>>(
        user_embedding, supp_users, wk, Ksupp,
        item_embedding, history, history_len, wq, qbuf);
    attn_kernel<<<NH * BB / 4, 256, 0, stream>>>(Ksupp, qbuf, sample_index, wv, gat);
    epilogue_kernel<<<BB / 4, 256, 0, stream>>>(
        gat, item_embedding, w_out, l1_w, l1_b, l2_w, l2_b, l3_w, l3_b,
        user_bias, item_bias, x, out);
}

// Round 7
// 218.501 us; speedup vs baseline: 1.0057x; 1.0057x over previous
//
#include <hip/hip_runtime.h>
#include <hip/hip_fp16.h>
#include <math.h>

#define N_USERS 1000000
#define N_ITEMS 100000
#define EMB 16
#define OUTD 16
#define NH 4
#define HID 32
#define BB 8192
#define SS 200
#define LL 50
#define NSUPP 50000
#define KS_BLOCKS (NSUPP / 16)   // 3125

typedef float v4f __attribute__((ext_vector_type(4)));
typedef _Float16 h4 __attribute__((ext_vector_type(4)));

// DPP cross-lane helpers (VALU pipe, no LDS). quad_perm xor1=0xB1, xor2=0x4E;
// row_ror:4=0x124, row_ror:8=0x128 (valid butterfly for sum/max within a
// 16-lane row, quad-class preserving).
#define DPPF(x, ctrl) \
    __int_as_float(__builtin_amdgcn_update_dpp(0, __float_as_int(x), ctrl, 0xF, 0xF, true))

// ---------------------------------------------------------------------------
// Fused setup: blocks [0, KS_BLOCKS) build Ksupp (fp16); the rest build qbuf.
// ---------------------------------------------------------------------------
__global__ __launch_bounds__(256) void setup_kernel(
    const float* __restrict__ user_emb,
    const int*   __restrict__ supp_users,
    const float* __restrict__ wk,
    _Float16*    __restrict__ Ksupp,
    const float* __restrict__ item_emb,
    const int*   __restrict__ history,
    const int*   __restrict__ history_len,
    const float* __restrict__ wq,
    float*       __restrict__ qbuf)
{
    int t = threadIdx.x;
    if (blockIdx.x < KS_BLOCKS) {
        // ---- K_supp[h][n][o] = sum_e U[supp[n]][e] * wk[h][e][o], 16 n/block
        __shared__ float s_wk[NH * EMB * OUTD];
        __shared__ float s_u[16][EMB];
        for (int i = t; i < NH * EMB * OUTD; i += 256) s_wk[i] = wk[i];
        int n0 = blockIdx.x * 16;
        {
            int ul = t >> 4, e = t & 15;
            int row = supp_users[n0 + ul];
            s_u[ul][e] = user_emb[(size_t)row * EMB + e];
        }
        __syncthreads();
        int h   = t >> 6;
        int sub = (t >> 4) & 3;
        int o   = t & 15;
#pragma unroll
        for (int r = 0; r < 4; ++r) {
            int ul = sub + 4 * r;
            float acc = 0.f;
#pragma unroll
            for (int e = 0; e < EMB; ++e)
                acc += s_u[ul][e] * s_wk[(h * EMB + e) * OUTD + o];
            Ksupp[((size_t)h * NSUPP + n0 + ul) * OUTD + o] = (_Float16)acc;
        }
    } else {
        // ---- user_init + q: 4 b per block
        __shared__ float s_ui[4][EMB];
        __shared__ float s_wq[NH * EMB * OUTD];
        for (int i = t; i < NH * EMB * OUTD; i += 256) s_wq[i] = wq[i];

        int g    = t >> 6;
        int lane = t & 63;
        int l4   = lane >> 4;
        int e    = lane & 15;
        int b    = (blockIdx.x - KS_BLOCKS) * 4 + g;

        float sum = 0.f;
        for (int l = l4; l < LL; l += 4) {
            int it = __builtin_nontemporal_load(history + (size_t)b * LL + l);
            sum += item_emb[(size_t)it * EMB + e];
        }
        sum += __shfl_xor(sum, 16);
        sum += __shfl_xor(sum, 32);
        if (lane < EMB) s_ui[g][lane] = sum / (float)history_len[b];
        __syncthreads();

        int h = (t >> 4) & 3;
        int o = t & 15;
        float acc = 0.f;
#pragma unroll
        for (int ee = 0; ee < EMB; ++ee)
            acc += s_ui[g][ee] * s_wq[(h * EMB + ee) * OUTD + o];
        qbuf[((size_t)b * NH + h) * OUTD + o] = acc;
    }
}

// ---------------------------------------------------------------------------
// Attention per (h, b): one wave per b, one head per block.
// fp16 Ksupp: 1.6 MB per head slab -> per-XCD L2 resident (the R6 analysis:
// 0.24 lines/cyc/CU at ~208 in-flight => ~850 cyc effective latency = L3.
// Shrinking the slab 2x targets L2-hit latency ~220 cyc).
// Quad-cooperative gather: quad of 4 lanes covers one 32-B row (8 B/lane).
// ---------------------------------------------------------------------------
__global__ __launch_bounds__(256, 6) void attn_kernel(
    const _Float16* __restrict__ Ksupp,
    const float*    __restrict__ qbuf,
    const int*      __restrict__ sample_index,
    const float*    __restrict__ wv,
    float*          __restrict__ gat)
{
    int blk   = blockIdx.x;
    int h     = (blk & 7) >> 1;
    int btile = ((blk >> 3) << 1) | (blk & 1);
    int wave  = threadIdx.x >> 6;
    int lane  = threadIdx.x & 63;
    int b     = btile * 4 + wave;
    int g     = lane >> 2;      // row slot within a round (16 per round)
    int qt    = lane & 3;       // 8-B quarter of the 32-B row

    // per-quad direct index loads (same-address broadcast within quad)
    const int* si = sample_index + ((size_t)h * BB + b) * SS;
    int idx[13];
#pragma unroll
    for (int r = 0; r < 13; ++r) {
        int s = r * 16 + g;
        if (s > SS - 1) s = SS - 1;          // r=12, g>=8: clamped, masked below
        idx[r] = __builtin_nontemporal_load(si + s);
    }

    v4f qv = __builtin_nontemporal_load(
        (const v4f*)(qbuf + ((size_t)b * NH + h) * OUTD) + qt);

    const _Float16* Kh = Ksupp + (size_t)h * NSUPP * OUTD;

    // all 13 quad-cooperative gathers in flight (26 VGPRs total)
    h4 kq[13];
#pragma unroll
    for (int r = 0; r < 13; ++r)
        kq[r] = *(const h4*)(Kh + (size_t)idx[r] * OUTD + qt * 4);

    // scores: quarter-dot (fp32) + intra-quad DPP reduce
    float d[13];
#pragma unroll
    for (int r = 0; r < 13; ++r) {
        float p = (float)kq[r].x * qv.x + (float)kq[r].y * qv.y
                + (float)kq[r].z * qv.z + (float)kq[r].w * qv.w;
        p += DPPF(p, 0xB1);
        p += DPPF(p, 0x4E);
        d[r] = p;
    }
    if (g >= 8) d[12] = -3.0e38f;            // only s<200 valid in round 12

    // wave max: row_ror DPP then xor16/xor32
    float m = d[0];
#pragma unroll
    for (int r = 1; r < 13; ++r) m = fmaxf(m, d[r]);
    m = fmaxf(m, DPPF(m, 0x124));
    m = fmaxf(m, DPPF(m, 0x128));
    m = fmaxf(m, __shfl_xor(m, 16));
    m = fmaxf(m, __shfl_xor(m, 32));

    // weights + context quarter accumulation (K rows still live in regs)
    float l = 0.f;
    v4f c = {0.f, 0.f, 0.f, 0.f};
#pragma unroll
    for (int r = 0; r < 13; ++r) {
        float w = __expf(d[r] - m);          // exactly 0 for masked slots
        l += w;
        c.x += w * (float)kq[r].x;
        c.y += w * (float)kq[r].y;
        c.z += w * (float)kq[r].z;
        c.w += w * (float)kq[r].w;
    }
    // cross-group reduce (qt-preserving)
    l   += DPPF(l,   0x124); l   += DPPF(l,   0x128);
    c.x += DPPF(c.x, 0x124); c.x += DPPF(c.x, 0x128);
    c.y += DPPF(c.y, 0x124); c.y += DPPF(c.y, 0x128);
    c.z += DPPF(c.z, 0x124); c.z += DPPF(c.z, 0x128);
    c.w += DPPF(c.w, 0x124); c.w += DPPF(c.w, 0x128);
    l   += __shfl_xor(l,   16); l   += __shfl_xor(l,   32);
    c.x += __shfl_xor(c.x, 16); c.x += __shfl_xor(c.x, 32);
    c.y += __shfl_xor(c.y, 16); c.y += __shfl_xor(c.y, 32);
    c.z += __shfl_xor(c.z, 16); c.z += __shfl_xor(c.z, 32);
    c.w += __shfl_xor(c.w, 16); c.w += __shfl_xor(c.w, 32);
    float inv = 1.f / l;

    // gat[b][h*16+g]: group g owns output column g
    float part = c.x * wv[((size_t)h * OUTD + qt * 4 + 0) * OUTD + g]
               + c.y * wv[((size_t)h * OUTD + qt * 4 + 1) * OUTD + g]
               + c.z * wv[((size_t)h * OUTD + qt * 4 + 2) * OUTD + g]
               + c.w * wv[((size_t)h * OUTD + qt * 4 + 3) * OUTD + g];
    part += DPPF(part, 0xB1);
    part += DPPF(part, 0x4E);
    if (qt == 0)
        gat[(size_t)b * (NH * OUTD) + h * OUTD + g] = part * inv;
}

// ---------------------------------------------------------------------------
// Epilogue per b (4 b per 256-thread block, one wave per b).
// ---------------------------------------------------------------------------
__global__ __launch_bounds__(256) void epilogue_kernel(
    const float* __restrict__ gat,
    const float* __restrict__ item_emb,
    const float* __restrict__ w_out,
    const float* __restrict__ l1_w, const float* __restrict__ l1_b,
    const float* __restrict__ l2_w, const float* __restrict__ l2_b,
    const float* __restrict__ l3_w, const float* __restrict__ l3_b,
    const float* __restrict__ user_bias, const float* __restrict__ item_bias,
    const int*   __restrict__ x,
    float*       __restrict__ out)
{
    int t    = threadIdx.x;
    int g    = t >> 6;
    int lane = t & 63;
    int b    = blockIdx.x * 4 + g;

    __shared__ float s_gat[4][NH * OUTD];
    __shared__ float s_ue[4][OUTD];
    __shared__ float s_ie[4][EMB];
    __shared__ float s_x1[4][HID];
    __shared__ float s_x2[4][HID / 2];

    int uid = x[(size_t)b * 2 + 0];
    int iid = x[(size_t)b * 2 + 1];

    s_gat[g][lane] = gat[(size_t)b * (NH * OUTD) + lane];
    if (lane < EMB) s_ie[g][lane] = item_emb[(size_t)iid * EMB + lane];
    __syncthreads();

    if (lane < OUTD) {
        float acc = 0.f;
#pragma unroll
        for (int j = 0; j < NH * OUTD; ++j) acc += s_gat[g][j] * w_out[j * OUTD + lane];
        s_ue[g][lane] = acc;
    }
    __syncthreads();

    if (lane < HID) {
        float acc = l1_b[lane];
#pragma unroll
        for (int i = 0; i < EMB; ++i) {
            float ue = s_ue[g][i], ie = s_ie[g][i];
            acc += ue * l1_w[i * HID + lane]
                 + ie * l1_w[(EMB + i) * HID + lane]
                 + ue * ie * l1_w[(2 * EMB + i) * HID + lane];
        }
        s_x1[g][lane] = tanhf(acc);
    }
    __syncthreads();

    if (lane < HID / 2) {
        float acc = l2_b[lane];
#pragma unroll
        for (int j = 0; j < HID; ++j) acc += s_x1[g][j] * l2_w[j * (HID / 2) + lane];
        s_x2[g][lane] = tanhf(acc);
    }
    __syncthreads();

    if (lane == 0) {
        float x3 = l3_b[0];
#pragma unroll
        for (int j = 0; j < HID / 2; ++j) x3 += s_x2[g][j] * l3_w[j];
        float ratings = 0.f;
#pragma unroll
        for (int o = 0; o < OUTD; ++o) ratings += s_ue[g][o] * s_ie[g][o];
        out[b] = 0.5f * (ratings + x3) + user_bias[uid] + item_bias[iid];
    }
}

// ---------------------------------------------------------------------------
extern "C" void kernel_launch(void* const* d_in, const int* in_sizes, int n_in,
                              void* d_out, int out_size, void* d_ws, size_t ws_size,
                              hipStream_t stream) {
    const float* user_embedding = (const float*)d_in[0];
    const float* item_embedding = (const float*)d_in[1];
    const float* wq             = (const float*)d_in[2];
    const float* wk             = (const float*)d_in[3];
    const float* wv             = (const float*)d_in[4];
    const float* w_out          = (const float*)d_in[5];
    const float* l1_w           = (const float*)d_in[6];
    const float* l1_b           = (const float*)d_in[7];
    const float* l2_w           = (const float*)d_in[8];
    const float* l2_b           = (const float*)d_in[9];
    const float* l3_w           = (const float*)d_in[10];
    const float* l3_b           = (const float*)d_in[11];
    const float* user_bias      = (const float*)d_in[12];
    const float* item_bias      = (const float*)d_in[13];
    const int*   x              = (const int*)d_in[14];
    const int*   history        = (const int*)d_in[15];
    const int*   history_len    = (const int*)d_in[16];
    const int*   supp_users     = (const int*)d_in[17];
    const int*   sample_index   = (const int*)d_in[18];
    float* out = (float*)d_out;

    char* ws = (char*)d_ws;
    _Float16* Ksupp = (_Float16*)ws;                              // 6.4 MB
    ws += (size_t)NH * NSUPP * OUTD * sizeof(_Float16);
    float* qbuf  = (float*)ws;                                    // 2 MB
    ws += (size_t)BB * NH * OUTD * sizeof(float);
    float* gat   = (float*)ws;                                    // 2 MB

    setup_kernel<<<KS_BLOCKS + BB / 4, 256, 0, stream>>>(
        user_embedding, supp_users, wk, Ksupp,
        item_embedding, history, history_len, wq, qbuf);
    attn_kernel<<<NH * BB / 4, 256, 0, stream>>>(Ksupp, qbuf, sample_index, wv, gat);
    epilogue_kernel<<<BB / 4, 256, 0, stream>>>(
        gat, item_embedding, w_out, l1_w, l1_b, l2_w, l2_b, l3_w, l3_b,
        user_bias, item_bias, x, out);
}